// Round 5
// baseline (534.387 us; speedup 1.0000x reference)
//
#include <hip/hip_runtime.h>
#include <hip/hip_bf16.h>
#include <stdint.h>
#include <math.h>

typedef __bf16 bf16_t;
typedef __bf16 bf16x8 __attribute__((ext_vector_type(8)));
typedef __bf16 bf16x4 __attribute__((ext_vector_type(4)));
typedef float  f32x4  __attribute__((ext_vector_type(4)));

// Problem constants: B=16,H=64,W=80,C=256; GH=8,GW=10; heads=8,DH=32; INNER=1024
//
// FRAG layout (both A and B^T operands), for X[M rows][K cols], K32=K/32:
//   element (m,k): g=m>>4, lnr=m&15, kk=k>>5, q=(k&31)>>3, j=k&7
//   addr = ((g*K32 + kk)*64 + q*16 + lnr)*8 + j
// A wave (lane = q*16+lnr) then loads one MFMA fragment as ONE contiguous 1KB read:
//   frag(g,kk) = base + ((g*K32+kk)*64 + lane)*8   [8 bf16/lane]

__device__ __forceinline__ int map_p_to_g(int p) {
    int w = p / 80, n = p - w * 80;
    int b  = w >> 6, h2 = (w >> 3) & 7, w2 = w & 7;
    int gh = n / 10, gw = n - gh * 10;
    return b * 5120 + (gh * 8 + h2) * 80 + (gw * 8 + w2);
}

// ---------------- weight convert: fp32 [K][N] -> bf16 frag layout of Bt[N][K] ----------------
__global__ __launch_bounds__(256) void wconv_k(const float* __restrict__ in,
                                               bf16_t* __restrict__ out, int N, int K32)
{
    int c  = blockIdx.x * 256 + threadIdx.x;   // chunk id; grid = N*K32*4 / 256? (N*K/8/256)
    int gk = c >> 6, l = c & 63;
    int kk = gk % K32, g = gk / K32;
    int n  = g * 16 + (l & 15);
    int kb = kk * 32 + (l >> 4) * 8;
    bf16x8 v;
#pragma unroll
    for (int j = 0; j < 8; ++j)
        v[j] = (bf16_t)in[(size_t)(kb + j) * N + n];
    *(bf16x8*)(out + (size_t)c * 8) = v;
}

// ---------------- LayerNorm (one wave per row) -> frag-layout output (K=256) ----------------
template <int PERM>
__global__ __launch_bounds__(256) void ln_k(const float* __restrict__ in,
                                            const float* __restrict__ gg,
                                            const float* __restrict__ bb,
                                            bf16_t* __restrict__ o)
{
    int row  = blockIdx.x * 4 + (threadIdx.x >> 6);
    int lane = threadIdx.x & 63;
    const float4 xv = *(const float4*)(in + (size_t)row * 256 + lane * 4);
    float s = xv.x + xv.y + xv.z + xv.w;
#pragma unroll
    for (int m = 1; m < 64; m <<= 1) s += __shfl_xor(s, m, 64);
    float mean = s * (1.f / 256.f);
    float d0 = xv.x - mean, d1 = xv.y - mean, d2 = xv.z - mean, d3 = xv.w - mean;
    float v = d0 * d0 + d1 * d1 + d2 * d2 + d3 * d3;
#pragma unroll
    for (int m = 1; m < 64; m <<= 1) v += __shfl_xor(v, m, 64);
    float rstd = rsqrtf(v * (1.f / 256.f) + 1e-5f);
    const float4 gv = *(const float4*)(gg + lane * 4);
    const float4 bv = *(const float4*)(bb + lane * 4);
    int orow = row;
    if (PERM) {
        int b = row / 5120, r1 = row - b * 5120;
        int h = r1 / 80, wv = r1 - h * 80;
        int gh = h >> 3, h2 = h & 7, gw = wv >> 3, w2 = wv & 7;
        orow = ((b * 8 + h2) * 8 + w2) * 80 + gh * 10 + gw;
    }
    bf16x4 ov;
    ov[0] = (bf16_t)(d0 * rstd * gv.x + bv.x);
    ov[1] = (bf16_t)(d1 * rstd * gv.y + bv.y);
    ov[2] = (bf16_t)(d2 * rstd * gv.z + bv.z);
    ov[3] = (bf16_t)(d3 * rstd * gv.w + bv.w);
    // frag-layout store: lane holds elems k0=lane*4..+3
    int g   = orow >> 4, lnr = orow & 15;
    int kk  = lane >> 3;           // k0>>5
    int q   = (lane >> 1) & 3;     // (k0&31)>>3
    int j   = (lane & 1) * 4;      // k0&7
    size_t addr = (((size_t)g * 8 + kk) * 64 + q * 16 + lnr) * 8 + j;
    *(bf16x4*)(o + addr) = ov;
}

// ---------------- fragment-direct GEMM: no LDS, no barriers ----------------
// Block = 4 waves = 64 rows x 256 cols; wave tile 64x64 (4x4 frags of 16x16x32).
// A fragments identical across waves (L1 broadcast); B from L2-resident frag weights.
// EPI 0: bf16 plain out[row][N] = acc+bias                  [qkv]
// EPI 1: fp32 out = x[g] + ls*(acc+bias), grid-reverse map  [proj]
// EPI 2: h1f frag (K32out=32) = gelu(acc+bias)              [fc1]
// EPI 3: fp32 out[row][256] += ls*(acc+bias)                [fc2]
template <int K32, int EPI>
__global__ __launch_bounds__(256, 4) void gemm_fd(const bf16_t* __restrict__ Af,
                                                  const bf16_t* __restrict__ Bf,
                                                  const float* __restrict__ bias,
                                                  const float* __restrict__ xres,
                                                  const float* __restrict__ ls,
                                                  void* __restrict__ outp, int N)
{
    const int t = threadIdx.x, wid = t >> 6, lane = t & 63;
    const int ln = lane & 15, kg = lane >> 4;
    const int by = blockIdx.y, bx = blockIdx.x;

    const bf16_t* Ap = Af + ((size_t)by * 4 * K32) * 512 + lane * 8;
    const bf16_t* Bp = Bf + ((size_t)(bx * 16 + wid * 4) * K32) * 512 + lane * 8;

    const f32x4 fz = {0.f, 0.f, 0.f, 0.f};
    f32x4 acc[4][4];
#pragma unroll
    for (int i = 0; i < 4; ++i)
#pragma unroll
        for (int j = 0; j < 4; ++j) acc[i][j] = fz;

#pragma unroll 4
    for (int kk = 0; kk < K32; ++kk) {
        bf16x8 av[4], bv[4];
#pragma unroll
        for (int mt = 0; mt < 4; ++mt)
            av[mt] = *(const bf16x8*)(Ap + (size_t)(mt * K32 + kk) * 512);
#pragma unroll
        for (int nt = 0; nt < 4; ++nt)
            bv[nt] = *(const bf16x8*)(Bp + (size_t)(nt * K32 + kk) * 512);
#pragma unroll
        for (int mt = 0; mt < 4; ++mt)
#pragma unroll
            for (int nt = 0; nt < 4; ++nt)
                acc[mt][nt] = __builtin_amdgcn_mfma_f32_16x16x32_bf16(av[mt], bv[nt], acc[mt][nt], 0, 0, 0);
    }

#pragma unroll
    for (int mt = 0; mt < 4; ++mt) {
        const int rowb = by * 64 + mt * 16 + kg * 4;
#pragma unroll
        for (int nt = 0; nt < 4; ++nt) {
            const int col = bx * 256 + wid * 64 + nt * 16 + ln;
            const f32x4 a = acc[mt][nt];
            const float bsv = bias[col];
            if constexpr (EPI == 0) {
                bf16_t* o = (bf16_t*)outp;
#pragma unroll
                for (int r = 0; r < 4; ++r)
                    o[(size_t)(rowb + r) * N + col] = (bf16_t)(a[r] + bsv);
            } else if constexpr (EPI == 1) {
                const float lsv = ls[col];
                float* o = (float*)outp;
#pragma unroll
                for (int r = 0; r < 4; ++r) {
                    int g = map_p_to_g(rowb + r);
                    size_t idx = (size_t)g * 256 + col;
                    o[idx] = xres[idx] + lsv * (a[r] + bsv);
                }
            } else if constexpr (EPI == 2) {
                bf16_t* o = (bf16_t*)outp;   // h1f frag layout, K=1024 -> K32out=32
                const int gq = (col & 31) >> 3, jq = col & 7, kkq = col >> 5;
#pragma unroll
                for (int r = 0; r < 4; ++r) {
                    float u  = a[r] + bsv;
                    float gl = 0.5f * u * (1.f + erff(u * 0.70710678118654752f));
                    int row = rowb + r;
                    size_t addr = (((size_t)(row >> 4) * 32 + kkq) * 64 + gq * 16 + (row & 15)) * 8 + jq;
                    o[addr] = (bf16_t)gl;
                }
            } else {
                const float lsv = ls[col];
                float* o = (float*)outp;
#pragma unroll
                for (int r = 0; r < 4; ++r) {
                    size_t idx = (size_t)(rowb + r) * 256 + col;
                    o[idx] += lsv * (a[r] + bsv);
                }
            }
        }
    }
}

// ---------------- fused per-window attention ----------------
// Inputs: plain qkv [81920][768] (unchanged). Output: attno in FRAG layout (proj's A).
__global__ __launch_bounds__(256) void attn_k(const bf16_t* __restrict__ qkv,
                                              bf16_t* __restrict__ out)
{
    __shared__ bf16_t Plds[4 * 7040];
    const int t = threadIdx.x, wid = t >> 6, lane = t & 63;
    const int ln = lane & 15, kg = lane >> 4;
    bf16_t* P = &Plds[wid * 7040];
    const int w = blockIdx.x;
    const bf16_t* base = qkv + (size_t)w * 80 * 768;
    const float SCALE = 0.17677669529663689f;

    for (int hh = 0; hh < 2; ++hh) {
        const int h = wid + hh * 4;
        const bf16_t* hb = base + h * 96;
        bf16x8 qa[5], kb[5];
#pragma unroll
        for (int mt = 0; mt < 5; ++mt)
            qa[mt] = *(const bf16x8*)(hb + (size_t)(mt * 16 + ln) * 768 + kg * 8);
#pragma unroll
        for (int nt = 0; nt < 5; ++nt)
            kb[nt] = *(const bf16x8*)(hb + (size_t)(nt * 16 + ln) * 768 + 32 + kg * 8);
        f32x4 S[5][5];
#pragma unroll
        for (int mt = 0; mt < 5; ++mt)
#pragma unroll
            for (int nt = 0; nt < 5; ++nt) {
                f32x4 z = {0.f, 0.f, 0.f, 0.f};
                S[mt][nt] = __builtin_amdgcn_mfma_f32_16x16x32_bf16(qa[mt], kb[nt], z, 0, 0, 0);
            }
#pragma unroll
        for (int mt = 0; mt < 5; ++mt) {
#pragma unroll
            for (int r = 0; r < 4; ++r) {
                float mx = S[mt][0][r];
#pragma unroll
                for (int nt = 1; nt < 5; ++nt) mx = fmaxf(mx, S[mt][nt][r]);
                mx = fmaxf(mx, __shfl_xor(mx, 1, 64));
                mx = fmaxf(mx, __shfl_xor(mx, 2, 64));
                mx = fmaxf(mx, __shfl_xor(mx, 4, 64));
                mx = fmaxf(mx, __shfl_xor(mx, 8, 64));
                float sum = 0.f;
#pragma unroll
                for (int nt = 0; nt < 5; ++nt) {
                    float e = __expf((S[mt][nt][r] - mx) * SCALE);
                    S[mt][nt][r] = e;
                    sum += e;
                }
                sum += __shfl_xor(sum, 1, 64);
                sum += __shfl_xor(sum, 2, 64);
                sum += __shfl_xor(sum, 4, 64);
                sum += __shfl_xor(sum, 8, 64);
                float inv = 1.f / sum;
#pragma unroll
                for (int nt = 0; nt < 5; ++nt) S[mt][nt][r] *= inv;
            }
        }
#pragma unroll
        for (int mt = 0; mt < 5; ++mt)
#pragma unroll
            for (int nt = 0; nt < 5; ++nt)
#pragma unroll
                for (int r = 0; r < 4; ++r)
                    P[(mt * 16 + kg * 4 + r) * 88 + nt * 16 + ln] = (bf16_t)S[mt][nt][r];
        f32x4 O[5][2];
#pragma unroll
        for (int mt = 0; mt < 5; ++mt) {
            O[mt][0] = (f32x4){0.f, 0.f, 0.f, 0.f};
            O[mt][1] = (f32x4){0.f, 0.f, 0.f, 0.f};
        }
#pragma unroll
        for (int nt2 = 0; nt2 < 2; ++nt2) {
#pragma unroll
            for (int kt = 0; kt < 3; ++kt) {
                const bool dead = (kt == 2) && (kg >= 2);
                bf16x8 bv;
#pragma unroll
                for (int j = 0; j < 8; ++j) {
                    int tok = kt * 32 + kg * 8 + j;
                    if (tok > 79) tok = 79;
                    bv[j] = hb[(size_t)tok * 768 + 64 + nt2 * 16 + ln];
                }
                if (dead) {
#pragma unroll
                    for (int j = 0; j < 8; ++j) bv[j] = (bf16_t)0.f;
                }
                int cb = kt * 32 + kg * 8;
                if (cb >= 80) cb = 0;
#pragma unroll
                for (int mt = 0; mt < 5; ++mt) {
                    bf16x8 av = *(const bf16x8*)(P + (mt * 16 + ln) * 88 + cb);
                    O[mt][nt2] = __builtin_amdgcn_mfma_f32_16x16x32_bf16(av, bv, O[mt][nt2], 0, 0, 0);
                }
            }
        }
        // frag-layout store: element (row=w*80+mt*16+kg*4+r, col=h*32+nt2*16+ln), K32=8
#pragma unroll
        for (int mt = 0; mt < 5; ++mt)
#pragma unroll
            for (int nt2 = 0; nt2 < 2; ++nt2) {
                const int q16 = nt2 * 2 + (ln >> 3);
#pragma unroll
                for (int r = 0; r < 4; ++r) {
                    size_t addr = ((((size_t)w * 5 + mt) * 8 + h) * 64 + q16 * 16 + kg * 4 + r) * 8 + (ln & 7);
                    out[addr] = (bf16_t)O[mt][nt2][r];
                }
            }
    }
}

// ---------------- launch ----------------
extern "C" void kernel_launch(void* const* d_in, const int* in_sizes, int n_in,
                              void* d_out, int out_size, void* d_ws, size_t ws_size,
                              hipStream_t stream)
{
    (void)in_sizes; (void)n_in; (void)out_size; (void)ws_size;
    const float* x     = (const float*)d_in[0];
    const float* n1g   = (const float*)d_in[1];
    const float* n1b   = (const float*)d_in[2];
    const float* qkvw  = (const float*)d_in[3];
    const float* qkvb  = (const float*)d_in[4];
    const float* projw = (const float*)d_in[5];
    const float* projb = (const float*)d_in[6];
    const float* ls1   = (const float*)d_in[7];
    const float* n2g   = (const float*)d_in[8];
    const float* n2b   = (const float*)d_in[9];
    const float* fc1w  = (const float*)d_in[10];
    const float* fc1b  = (const float*)d_in[11];
    const float* fc2w  = (const float*)d_in[12];
    const float* fc2b  = (const float*)d_in[13];
    const float* ls2   = (const float*)d_in[14];
    float* out = (float*)d_out;

    // ws layout (bytes):
    //  [0, 42MB)      actA region: ln1p-frag -> attno-frag -> ln2-frag (sequential reuse)
    //  [42, 210MB)    big region: qkv plain (126MB) -> h1f frag (168MB) (sequential reuse)
    //  [210MB, ...)   frag weights ~1.6MB
    char* ws = (char*)d_ws;
    bf16_t* actA   = (bf16_t*)(ws);
    bf16_t* qkv    = (bf16_t*)(ws + 41943040ull);
    bf16_t* h1f    = (bf16_t*)(ws + 41943040ull);
    bf16_t* wbuf   = (bf16_t*)(ws + 209715200ull);
    bf16_t* qkvwt  = wbuf;                          // frag [768][256]   393216 B
    bf16_t* projwt = qkvwt + 768 * 256;             // frag [256][256]   131072 B
    bf16_t* fc1wt  = projwt + 256 * 256;            // frag [1024][256]  524288 B
    bf16_t* fc2wt  = fc1wt + 1024 * 256;            // frag [256][1024]  524288 B

    wconv_k<<<96,  256, 0, stream>>>(qkvw,  qkvwt, 768, 8);
    wconv_k<<<32,  256, 0, stream>>>(projw, projwt, 256, 8);
    wconv_k<<<128, 256, 0, stream>>>(fc1w,  fc1wt, 1024, 8);
    wconv_k<<<128, 256, 0, stream>>>(fc2w,  fc2wt, 256, 32);

    ln_k<1><<<20480, 256, 0, stream>>>(x, n1g, n1b, actA);
    gemm_fd<8, 0><<<dim3(3, 1280), 256, 0, stream>>>(actA, qkvwt, qkvb, nullptr, nullptr, qkv, 768);
    attn_k<<<1024, 256, 0, stream>>>(qkv, actA);
    gemm_fd<8, 1><<<dim3(1, 1280), 256, 0, stream>>>(actA, projwt, projb, x, ls1, out, 256);
    ln_k<0><<<20480, 256, 0, stream>>>(out, n2g, n2b, actA);
    gemm_fd<8, 2><<<dim3(4, 1280), 256, 0, stream>>>(actA, fc1wt, fc1b, nullptr, nullptr, h1f, 1024);
    gemm_fd<32, 3><<<dim3(1, 1280), 256, 0, stream>>>(h1f, fc2wt, fc2b, nullptr, ls2, out, 256);
}